// Round 1
// baseline (2822.207 us; speedup 1.0000x reference)
//
#include <hip/hip_runtime.h>
#include <math.h>

#define T_TOK 4096
#define H_DIM 1024
#define I_DIM 2048
#define E_NUM 8
#define BM 16
#define ICHUNK 256

// ---------------- Router: logits -> softmax -> top2 -> renormalized weights --
__global__ __launch_bounds__(256) void moe_router(
    const float* __restrict__ x, const float* __restrict__ gate,
    int* __restrict__ topk_idx, float* __restrict__ topk_w)
{
    const int wave = threadIdx.x >> 6;
    const int lane = threadIdx.x & 63;
    const int t = blockIdx.x * 4 + wave;   // one wave per token

    float acc[E_NUM];
#pragma unroll
    for (int e = 0; e < E_NUM; ++e) acc[e] = 0.f;
    const float* xp = x + (size_t)t * H_DIM;
    for (int k = lane; k < H_DIM; k += 64) {
        const float xv = xp[k];
#pragma unroll
        for (int e = 0; e < E_NUM; ++e) acc[e] += xv * gate[e * H_DIM + k];
    }
#pragma unroll
    for (int e = 0; e < E_NUM; ++e) {
#pragma unroll
        for (int off = 32; off > 0; off >>= 1)
            acc[e] += __shfl_xor(acc[e], off, 64);
    }
    if (lane == 0) {
        float m = acc[0];
#pragma unroll
        for (int e = 1; e < E_NUM; ++e) m = fmaxf(m, acc[e]);
        float p[E_NUM];
        float Z = 0.f;
#pragma unroll
        for (int e = 0; e < E_NUM; ++e) { p[e] = expf(acc[e] - m); Z += p[e]; }
        const float invZ = 1.f / Z;
        int i1 = 0, i2 = 0;
        float v1 = -1.f, v2 = -1.f;
#pragma unroll
        for (int e = 0; e < E_NUM; ++e) {
            const float pe = p[e] * invZ;
            if (pe > v1)      { v2 = v1; i2 = i1; v1 = pe; i1 = e; }
            else if (pe > v2) { v2 = pe; i2 = e; }
        }
        const float s = 1.f / (v1 + v2 + 1e-9f);
        topk_idx[t * 2 + 0] = i1; topk_idx[t * 2 + 1] = i2;
        topk_w[t * 2 + 0] = v1 * s; topk_w[t * 2 + 1] = v2 * s;
    }
}

// ---------------- Build per-expert token lists (order-free, atomics) ---------
__global__ void moe_build(
    const int* __restrict__ topk_idx, const float* __restrict__ topk_w,
    int* __restrict__ counts, int* __restrict__ list_tok, float* __restrict__ list_w)
{
    const int t = blockIdx.x * blockDim.x + threadIdx.x;
    if (t >= T_TOK) return;
#pragma unroll
    for (int k = 0; k < 2; ++k) {
        const int e = topk_idx[t * 2 + k];
        const float w = topk_w[t * 2 + k];
        const int pos = atomicAdd(&counts[e], 1);
        list_tok[e * T_TOK + pos] = t;
        list_w[e * T_TOK + pos] = w;
    }
}

// ---------------- Fused expert FFN: silu(X @ Wup) @ Wdown, scatter-add -------
// Block = 256 threads, handles BM=16 gathered token rows of one expert.
// LDS: X tile [16][1024] f32 (64 KB) + Hs chunk [16][256] f32 (16 KB) = 80 KB.
__global__ __launch_bounds__(256) void moe_ffn(
    const float* __restrict__ x, const float* __restrict__ w_up,
    const float* __restrict__ w_down, const int* __restrict__ counts,
    const int* __restrict__ list_tok, const float* __restrict__ list_w,
    float* __restrict__ out)
{
    __shared__ float Xs[BM][H_DIM];
    __shared__ float Hs[BM][ICHUNK];

    const int e = blockIdx.y;
    const int cnt = counts[e];
    const int row0 = blockIdx.x * BM;
    if (row0 >= cnt) return;                 // uniform early-exit, no barrier yet
    const int rows = min(BM, cnt - row0);
    const int tid = threadIdx.x;
    const int lbase = e * T_TOK + row0;

    // Stage gathered X rows (pad rows replicate last valid row; never written out)
    for (int r = 0; r < BM; ++r) {
        const int rr = (r < rows) ? r : (rows - 1);
        const int tok = list_tok[lbase + rr];
        const float4 v = ((const float4*)(x + (size_t)tok * H_DIM))[tid];
        ((float4*)&Xs[r][0])[tid] = v;
    }
    __syncthreads();

    float acc2[BM][4];
#pragma unroll
    for (int r = 0; r < BM; ++r)
#pragma unroll
        for (int j = 0; j < 4; ++j) acc2[r][j] = 0.f;

    const float* upP = w_up + (size_t)e * H_DIM * I_DIM;
    const float* dnP = w_down + (size_t)e * I_DIM * H_DIM;

    for (int ic = 0; ic < I_DIM / ICHUNK; ++ic) {
        // ---- phase 1: hmid chunk, thread owns column i = ic*256+tid, 16 rows
        const int i = ic * ICHUNK + tid;
        float acc1[BM];
#pragma unroll
        for (int r = 0; r < BM; ++r) acc1[r] = 0.f;
        const float* up = upP + i;
        for (int k = 0; k < H_DIM; k += 4) {
            const float w0 = up[(size_t)(k + 0) * I_DIM];
            const float w1 = up[(size_t)(k + 1) * I_DIM];
            const float w2 = up[(size_t)(k + 2) * I_DIM];
            const float w3 = up[(size_t)(k + 3) * I_DIM];
#pragma unroll
            for (int r = 0; r < BM; ++r) {
                const float4 xv = *(const float4*)&Xs[r][k];
                acc1[r] = fmaf(xv.x, w0, acc1[r]);
                acc1[r] = fmaf(xv.y, w1, acc1[r]);
                acc1[r] = fmaf(xv.z, w2, acc1[r]);
                acc1[r] = fmaf(xv.w, w3, acc1[r]);
            }
        }
        __syncthreads();                     // prior chunk's phase-2 done with Hs
#pragma unroll
        for (int r = 0; r < BM; ++r) {
            const float v = acc1[r];
            Hs[r][tid] = v / (1.f + expf(-v));   // silu
        }
        __syncthreads();

        // ---- phase 2: out += Hs @ Wdown-chunk, thread owns 4 cols (tid*4)
        for (int i4 = 0; i4 < ICHUNK; i4 += 4) {
            const size_t ib = (size_t)(ic * ICHUNK + i4);
            const float4 wd0 = *(const float4*)(dnP + (ib + 0) * H_DIM + tid * 4);
            const float4 wd1 = *(const float4*)(dnP + (ib + 1) * H_DIM + tid * 4);
            const float4 wd2 = *(const float4*)(dnP + (ib + 2) * H_DIM + tid * 4);
            const float4 wd3 = *(const float4*)(dnP + (ib + 3) * H_DIM + tid * 4);
#pragma unroll
            for (int r = 0; r < BM; ++r) {
                const float4 hv = *(const float4*)&Hs[r][i4];
                acc2[r][0] = fmaf(hv.x, wd0.x, fmaf(hv.y, wd1.x, fmaf(hv.z, wd2.x, fmaf(hv.w, wd3.x, acc2[r][0]))));
                acc2[r][1] = fmaf(hv.x, wd0.y, fmaf(hv.y, wd1.y, fmaf(hv.z, wd2.y, fmaf(hv.w, wd3.y, acc2[r][1]))));
                acc2[r][2] = fmaf(hv.x, wd0.z, fmaf(hv.y, wd1.z, fmaf(hv.z, wd2.z, fmaf(hv.w, wd3.z, acc2[r][2]))));
                acc2[r][3] = fmaf(hv.x, wd0.w, fmaf(hv.y, wd1.w, fmaf(hv.z, wd2.w, fmaf(hv.w, wd3.w, acc2[r][3]))));
            }
        }
    }

    // scatter-add weighted result (token appears in 2 expert lists -> atomics)
    for (int r = 0; r < rows; ++r) {
        const int tok = list_tok[lbase + r];
        const float w = list_w[lbase + r];
        float* op = out + (size_t)tok * H_DIM + tid * 4;
        atomicAdd(op + 0, w * acc2[r][0]);
        atomicAdd(op + 1, w * acc2[r][1]);
        atomicAdd(op + 2, w * acc2[r][2]);
        atomicAdd(op + 3, w * acc2[r][3]);
    }
}

extern "C" void kernel_launch(void* const* d_in, const int* in_sizes, int n_in,
                              void* d_out, int out_size, void* d_ws, size_t ws_size,
                              hipStream_t stream)
{
    const float* x      = (const float*)d_in[0];   // [T, H]
    const float* gate   = (const float*)d_in[1];   // [E, H]
    const float* w_up   = (const float*)d_in[2];   // [E, H, I]
    const float* w_down = (const float*)d_in[3];   // [E, I, H]
    float* out = (float*)d_out;                    // [T, H]

    char* ws = (char*)d_ws;
    int*   counts   = (int*)(ws + 0);                                   // 256 B
    int*   topk_idx = (int*)(ws + 256);                                 // 32 KB
    float* topk_w   = (float*)(ws + 256 + T_TOK * 2 * 4);               // 32 KB
    int*   list_tok = (int*)(ws + 256 + T_TOK * 4 * 4);                 // 128 KB
    float* list_w   = (float*)(ws + 256 + T_TOK * 4 * 4 + E_NUM * T_TOK * 4); // 128 KB

    hipMemsetAsync(counts, 0, 256, stream);
    hipMemsetAsync(out, 0, (size_t)out_size * sizeof(float), stream);

    moe_router<<<T_TOK / 4, 256, 0, stream>>>(x, gate, topk_idx, topk_w);
    moe_build<<<T_TOK / 256, 256, 0, stream>>>(topk_idx, topk_w, counts, list_tok, list_w);
    dim3 g(T_TOK / BM, E_NUM);
    moe_ffn<<<g, 256, 0, stream>>>(x, w_up, w_down, counts, list_tok, list_w, out);
}

// Round 4
// 470.016 us; speedup vs baseline: 6.0045x; 6.0045x over previous
//
#include <hip/hip_runtime.h>
#include <math.h>

#define T_TOK 4096
#define H_DIM 1024
#define I_DIM 2048
#define E_NUM 8
#define CAP   2048
#define BM 128
#define BN 128
#define BK 64

typedef __attribute__((ext_vector_type(8))) short bf16x8;
typedef __attribute__((ext_vector_type(4))) float f32x4;

__device__ __forceinline__ unsigned short f2bf(float f) {
    union { float f; unsigned int u; } v; v.f = f;
    unsigned int r = v.u + 0x7FFFu + ((v.u >> 16) & 1u);
    return (unsigned short)(r >> 16);
}

__device__ __forceinline__ void gl_lds16(const void* g, void* l) {
    __builtin_amdgcn_global_load_lds(
        (const __attribute__((address_space(1))) void*)g,
        (__attribute__((address_space(3))) void*)l, 16, 0, 0);
}

// ---------------- Router ----------------------------------------------------
__global__ __launch_bounds__(256) void moe_router(
    const float* __restrict__ x, const float* __restrict__ gate,
    int* __restrict__ topk_idx, float* __restrict__ topk_w)
{
    const int wave = threadIdx.x >> 6;
    const int lane = threadIdx.x & 63;
    const int t = blockIdx.x * 4 + wave;

    float acc[E_NUM];
#pragma unroll
    for (int e = 0; e < E_NUM; ++e) acc[e] = 0.f;
    const float* xp = x + (size_t)t * H_DIM;
    for (int k = lane; k < H_DIM; k += 64) {
        const float xv = xp[k];
#pragma unroll
        for (int e = 0; e < E_NUM; ++e) acc[e] += xv * gate[e * H_DIM + k];
    }
#pragma unroll
    for (int e = 0; e < E_NUM; ++e) {
#pragma unroll
        for (int off = 32; off > 0; off >>= 1)
            acc[e] += __shfl_xor(acc[e], off, 64);
    }
    if (lane == 0) {
        float m = acc[0];
#pragma unroll
        for (int e = 1; e < E_NUM; ++e) m = fmaxf(m, acc[e]);
        float p[E_NUM]; float Z = 0.f;
#pragma unroll
        for (int e = 0; e < E_NUM; ++e) { p[e] = expf(acc[e] - m); Z += p[e]; }
        const float invZ = 1.f / Z;
        int i1 = 0, i2 = 0; float v1 = -1.f, v2 = -1.f;
#pragma unroll
        for (int e = 0; e < E_NUM; ++e) {
            const float pe = p[e] * invZ;
            if (pe > v1)      { v2 = v1; i2 = i1; v1 = pe; i1 = e; }
            else if (pe > v2) { v2 = pe; i2 = e; }
        }
        const float s = 1.f / (v1 + v2 + 1e-9f);
        topk_idx[t * 2 + 0] = i1; topk_idx[t * 2 + 1] = i2;
        topk_w[t * 2 + 0] = v1 * s; topk_w[t * 2 + 1] = v2 * s;
    }
}

// ---------------- Build per-expert token lists ------------------------------
__global__ void moe_build(
    const int* __restrict__ topk_idx, const float* __restrict__ topk_w,
    int* __restrict__ counts, int* __restrict__ list_tok, float* __restrict__ list_w)
{
    const int t = blockIdx.x * blockDim.x + threadIdx.x;
    if (t >= T_TOK) return;
#pragma unroll
    for (int k = 0; k < 2; ++k) {
        const int e = topk_idx[t * 2 + k];
        const float w = topk_w[t * 2 + k];
        const int pos = atomicAdd(&counts[e], 1);
        if (pos < CAP) {
            list_tok[e * CAP + pos] = t;
            list_w[e * CAP + pos] = w;
        }
    }
}

// ---------------- Gather X rows -> bf16 Xg[e][CAP][H] -----------------------
__global__ __launch_bounds__(256) void moe_gather(
    const float* __restrict__ x, const int* __restrict__ counts,
    const int* __restrict__ list_tok, unsigned short* __restrict__ Xg)
{
    const int e = blockIdx.y;
    const int r = blockIdx.x;
    if (r >= min(counts[e], CAP)) return;
    const int tok = list_tok[e * CAP + r];
    const float4 v = ((const float4*)(x + (size_t)tok * H_DIM))[threadIdx.x];
    ushort4 o = make_ushort4(f2bf(v.x), f2bf(v.y), f2bf(v.z), f2bf(v.w));
    *(ushort4*)(Xg + (size_t)(e * CAP + r) * H_DIM + threadIdx.x * 4) = o;
}

// ---------------- Transpose-convert weights: [E][R][C] f32 -> [E][C][R] bf16
__global__ __launch_bounds__(256) void transpose_bf16(
    const float* __restrict__ in, unsigned short* __restrict__ outp, int R, int C)
{
    __shared__ unsigned short tile[32][33];
    const int e = blockIdx.z;
    const float* src = in + (size_t)e * R * C;
    unsigned short* dst = outp + (size_t)e * R * C;
    const int c0 = blockIdx.x * 32;
    const int r0 = blockIdx.y * 32;
    const int tx = threadIdx.x & 31, ty = threadIdx.x >> 5;
#pragma unroll
    for (int s = 0; s < 4; ++s)
        tile[ty + s * 8][tx] = f2bf(src[(size_t)(r0 + ty + s * 8) * C + c0 + tx]);
    __syncthreads();
#pragma unroll
    for (int s = 0; s < 4; ++s)
        dst[(size_t)(c0 + ty + s * 8) * R + r0 + tx] = tile[tx][ty + s * 8];
}

// ---------------- GEMM1: hmid = silu(Xg @ Wup), bf16 MFMA -------------------
__global__ __launch_bounds__(256) void moe_gemm1(
    const unsigned short* __restrict__ Xg, const unsigned short* __restrict__ WupT,
    const int* __restrict__ counts, unsigned short* __restrict__ hmid)
{
    __shared__ unsigned short As[BM][BK];
    __shared__ unsigned short Bs[BN][BK];
    const int e = blockIdx.z;
    const int cnt = min(counts[e], CAP);
    const int row0 = blockIdx.x * BM;
    if (row0 >= cnt) return;
    const int n0 = blockIdx.y * BN;
    const int tid = threadIdx.x;
    const int lane = tid & 63;
    const int wid = tid >> 6;
    const int wm = wid >> 1, wn = wid & 1;

    const unsigned short* Ae = Xg + (size_t)e * CAP * H_DIM;
    const unsigned short* Be = WupT + (size_t)e * (size_t)I_DIM * H_DIM;

    const int sub = lane >> 3;            // 0..7 rows within 1KB chunk
    const int kus = (lane & 7) * 8;       // ushort offset within 64-col row

    f32x4 acc[4][4];
#pragma unroll
    for (int m = 0; m < 4; ++m)
#pragma unroll
        for (int n = 0; n < 4; ++n) acc[m][n] = (f32x4){0.f, 0.f, 0.f, 0.f};

    for (int kt = 0; kt < H_DIM; kt += BK) {
#pragma unroll
        for (int c = 0; c < 4; ++c) {
            const int row = (c * 4 + wid) * 8 + sub;
            gl_lds16(Ae + (size_t)(row0 + row) * H_DIM + kt + kus,
                     (char*)&As[0][0] + (c * 4 + wid) * 1024);
            gl_lds16(Be + (size_t)(n0 + row) * H_DIM + kt + kus,
                     (char*)&Bs[0][0] + (c * 4 + wid) * 1024);
        }
        __syncthreads();
#pragma unroll
        for (int kk = 0; kk < BK; kk += 32) {
            const int koff = kk + 8 * (lane >> 4);
            bf16x8 a[4], b[4];
#pragma unroll
            for (int m = 0; m < 4; ++m)
                a[m] = *(const bf16x8*)&As[wm * 64 + m * 16 + (lane & 15)][koff];
#pragma unroll
            for (int n = 0; n < 4; ++n)
                b[n] = *(const bf16x8*)&Bs[wn * 64 + n * 16 + (lane & 15)][koff];
#pragma unroll
            for (int m = 0; m < 4; ++m)
#pragma unroll
                for (int n = 0; n < 4; ++n)
                    acc[m][n] = __builtin_amdgcn_mfma_f32_16x16x32_bf16(
                        a[m], b[n], acc[m][n], 0, 0, 0);
        }
        __syncthreads();
    }

    unsigned short* He = hmid + (size_t)e * CAP * I_DIM;
#pragma unroll
    for (int m = 0; m < 4; ++m) {
        const int rb = row0 + wm * 64 + m * 16 + ((lane >> 4) << 2);
#pragma unroll
        for (int n = 0; n < 4; ++n) {
            const int col = n0 + wn * 64 + n * 16 + (lane & 15);
#pragma unroll
            for (int j = 0; j < 4; ++j) {
                const float v = acc[m][n][j];
                const float s = v / (1.f + __expf(-v));
                He[(size_t)(rb + j) * I_DIM + col] = f2bf(s);
            }
        }
    }
}

// ---------------- GEMM2: out += w * (hmid @ Wdown), atomic scatter ----------
__global__ __launch_bounds__(256) void moe_gemm2(
    const unsigned short* __restrict__ hmid, const unsigned short* __restrict__ WdownT,
    const int* __restrict__ counts, const int* __restrict__ list_tok,
    const float* __restrict__ list_w, float* __restrict__ out)
{
    __shared__ unsigned short As[BM][BK];
    __shared__ unsigned short Bs[BN][BK];
    const int e = blockIdx.z;
    const int cnt = min(counts[e], CAP);
    const int row0 = blockIdx.x * BM;
    if (row0 >= cnt) return;
    const int n0 = blockIdx.y * BN;
    const int tid = threadIdx.x;
    const int lane = tid & 63;
    const int wid = tid >> 6;
    const int wm = wid >> 1, wn = wid & 1;

    const unsigned short* Ae = hmid + (size_t)e * CAP * I_DIM;
    const unsigned short* Be = WdownT + (size_t)e * (size_t)H_DIM * I_DIM;

    const int sub = lane >> 3;
    const int kus = (lane & 7) * 8;

    f32x4 acc[4][4];
#pragma unroll
    for (int m = 0; m < 4; ++m)
#pragma unroll
        for (int n = 0; n < 4; ++n) acc[m][n] = (f32x4){0.f, 0.f, 0.f, 0.f};

    for (int kt = 0; kt < I_DIM; kt += BK) {
#pragma unroll
        for (int c = 0; c < 4; ++c) {
            const int row = (c * 4 + wid) * 8 + sub;
            gl_lds16(Ae + (size_t)(row0 + row) * I_DIM + kt + kus,
                     (char*)&As[0][0] + (c * 4 + wid) * 1024);
            gl_lds16(Be + (size_t)(n0 + row) * I_DIM + kt + kus,
                     (char*)&Bs[0][0] + (c * 4 + wid) * 1024);
        }
        __syncthreads();
#pragma unroll
        for (int kk = 0; kk < BK; kk += 32) {
            const int koff = kk + 8 * (lane >> 4);
            bf16x8 a[4], b[4];
#pragma unroll
            for (int m = 0; m < 4; ++m)
                a[m] = *(const bf16x8*)&As[wm * 64 + m * 16 + (lane & 15)][koff];
#pragma unroll
            for (int n = 0; n < 4; ++n)
                b[n] = *(const bf16x8*)&Bs[wn * 64 + n * 16 + (lane & 15)][koff];
#pragma unroll
            for (int m = 0; m < 4; ++m)
#pragma unroll
                for (int n = 0; n < 4; ++n)
                    acc[m][n] = __builtin_amdgcn_mfma_f32_16x16x32_bf16(
                        a[m], b[n], acc[m][n], 0, 0, 0);
        }
        __syncthreads();
    }

#pragma unroll
    for (int m = 0; m < 4; ++m) {
#pragma unroll
        for (int j = 0; j < 4; ++j) {
            const int gr = row0 + wm * 64 + m * 16 + ((lane >> 4) << 2) + j;
            if (gr < cnt) {
                const int tok = list_tok[e * CAP + gr];
                const float w = list_w[e * CAP + gr];
                float* op = out + (size_t)tok * H_DIM + n0 + wn * 64 + (lane & 15);
#pragma unroll
                for (int n = 0; n < 4; ++n)
                    atomicAdd(op + n * 16, w * acc[m][n][j]);
            }
        }
    }
}

extern "C" void kernel_launch(void* const* d_in, const int* in_sizes, int n_in,
                              void* d_out, int out_size, void* d_ws, size_t ws_size,
                              hipStream_t stream)
{
    const float* x      = (const float*)d_in[0];   // [T, H]
    const float* gate   = (const float*)d_in[1];   // [E, H]
    const float* w_up   = (const float*)d_in[2];   // [E, H, I]
    const float* w_down = (const float*)d_in[3];   // [E, I, H]
    float* out = (float*)d_out;                    // [T, H]

    char* ws = (char*)d_ws;
    int*   counts   = (int*)(ws);                          // 1 KB
    int*   topk_idx = (int*)(ws + 1024);                   // 32 KB
    float* topk_w   = (float*)(ws + 33792);                // 32 KB
    int*   list_tok = (int*)(ws + 66560);                  // 64 KB
    float* list_w   = (float*)(ws + 132096);               // 64 KB
    unsigned short* Xg     = (unsigned short*)(ws + 197632);                  // 32 MB
    unsigned short* WupT   = (unsigned short*)(ws + 197632 + 33554432ull);    // 32 MB
    unsigned short* WdownT = (unsigned short*)(ws + 197632 + 67108864ull);    // 32 MB
    unsigned short* hmid   = (unsigned short*)(ws + 197632 + 100663296ull);   // 64 MB

    hipMemsetAsync(counts, 0, 1024, stream);
    hipMemsetAsync(out, 0, (size_t)out_size * sizeof(float), stream);

    moe_router<<<T_TOK / 4, 256, 0, stream>>>(x, gate, topk_idx, topk_w);
    moe_build<<<T_TOK / 256, 256, 0, stream>>>(topk_idx, topk_w, counts, list_tok, list_w);
    moe_gather<<<dim3(CAP, E_NUM), 256, 0, stream>>>(x, counts, list_tok, Xg);
    transpose_bf16<<<dim3(I_DIM / 32, H_DIM / 32, E_NUM), 256, 0, stream>>>(w_up, WupT, H_DIM, I_DIM);
    transpose_bf16<<<dim3(H_DIM / 32, I_DIM / 32, E_NUM), 256, 0, stream>>>(w_down, WdownT, I_DIM, H_DIM);
    moe_gemm1<<<dim3(CAP / BM, I_DIM / BN, E_NUM), 256, 0, stream>>>(Xg, WupT, counts, hmid);
    moe_gemm2<<<dim3(CAP / BM, H_DIM / BN, E_NUM), 256, 0, stream>>>(hmid, WdownT, counts, list_tok, list_w, out);
}

// Round 7
// 434.187 us; speedup vs baseline: 6.5000x; 1.0825x over previous
//
#include <hip/hip_runtime.h>
#include <math.h>

#define T_TOK 4096
#define H_DIM 1024
#define I_DIM 2048
#define E_NUM 8
#define CAP   2048
#define BM 128
#define BN 128
#define BK 64

typedef __attribute__((ext_vector_type(8))) short bf16x8;
typedef __attribute__((ext_vector_type(4))) float f32x4;

__device__ __forceinline__ unsigned short f2bf(float f) {
    union { float f; unsigned int u; } v; v.f = f;
    unsigned int r = v.u + 0x7FFFu + ((v.u >> 16) & 1u);
    return (unsigned short)(r >> 16);
}

__device__ __forceinline__ void gl_lds16(const void* g, void* l) {
    __builtin_amdgcn_global_load_lds(
        (const __attribute__((address_space(1))) void*)g,
        (__attribute__((address_space(3))) void*)l, 16, 0, 0);
}

// ---------------- Router ----------------------------------------------------
__global__ __launch_bounds__(256) void moe_router(
    const float* __restrict__ x, const float* __restrict__ gate,
    int* __restrict__ topk_idx, float* __restrict__ topk_w)
{
    const int wave = threadIdx.x >> 6;
    const int lane = threadIdx.x & 63;
    const int t = blockIdx.x * 4 + wave;

    float acc[E_NUM];
#pragma unroll
    for (int e = 0; e < E_NUM; ++e) acc[e] = 0.f;
    const float* xp = x + (size_t)t * H_DIM;
    for (int k = lane; k < H_DIM; k += 64) {
        const float xv = xp[k];
#pragma unroll
        for (int e = 0; e < E_NUM; ++e) acc[e] += xv * gate[e * H_DIM + k];
    }
#pragma unroll
    for (int e = 0; e < E_NUM; ++e) {
#pragma unroll
        for (int off = 32; off > 0; off >>= 1)
            acc[e] += __shfl_xor(acc[e], off, 64);
    }
    if (lane == 0) {
        float m = acc[0];
#pragma unroll
        for (int e = 1; e < E_NUM; ++e) m = fmaxf(m, acc[e]);
        float p[E_NUM]; float Z = 0.f;
#pragma unroll
        for (int e = 0; e < E_NUM; ++e) { p[e] = expf(acc[e] - m); Z += p[e]; }
        const float invZ = 1.f / Z;
        int i1 = 0, i2 = 0; float v1 = -1.f, v2 = -1.f;
#pragma unroll
        for (int e = 0; e < E_NUM; ++e) {
            const float pe = p[e] * invZ;
            if (pe > v1)      { v2 = v1; i2 = i1; v1 = pe; i1 = e; }
            else if (pe > v2) { v2 = pe; i2 = e; }
        }
        const float s = 1.f / (v1 + v2 + 1e-9f);
        topk_idx[t * 2 + 0] = i1; topk_idx[t * 2 + 1] = i2;
        topk_w[t * 2 + 0] = v1 * s; topk_w[t * 2 + 1] = v2 * s;
    }
}

// ---------------- Build per-expert token lists ------------------------------
__global__ void moe_build(
    const int* __restrict__ topk_idx, const float* __restrict__ topk_w,
    int* __restrict__ counts, int* __restrict__ list_tok, float* __restrict__ list_w)
{
    const int t = blockIdx.x * blockDim.x + threadIdx.x;
    if (t >= T_TOK) return;
#pragma unroll
    for (int k = 0; k < 2; ++k) {
        const int e = topk_idx[t * 2 + k];
        const float w = topk_w[t * 2 + k];
        const int pos = atomicAdd(&counts[e], 1);
        if (pos < CAP) {
            list_tok[e * CAP + pos] = t;
            list_w[e * CAP + pos] = w;
        }
    }
}

// ---------------- Gather X rows -> bf16 Xg[e][CAP][H] -----------------------
__global__ __launch_bounds__(256) void moe_gather(
    const float* __restrict__ x, const int* __restrict__ counts,
    const int* __restrict__ list_tok, unsigned short* __restrict__ Xg)
{
    const int e = blockIdx.y;
    const int r = blockIdx.x;
    if (r >= min(counts[e], CAP)) return;
    const int tok = list_tok[e * CAP + r];
    const float4 v = ((const float4*)(x + (size_t)tok * H_DIM))[threadIdx.x];
    ushort4 o = make_ushort4(f2bf(v.x), f2bf(v.y), f2bf(v.z), f2bf(v.w));
    *(ushort4*)(Xg + (size_t)(e * CAP + r) * H_DIM + threadIdx.x * 4) = o;
}

// ---------------- Transpose-convert weights: [E][R][C] f32 -> [E][C][R] bf16
__global__ __launch_bounds__(256) void transpose_bf16(
    const float* __restrict__ in, unsigned short* __restrict__ outp, int R, int C)
{
    __shared__ unsigned short tile[32][33];
    const int e = blockIdx.z;
    const float* src = in + (size_t)e * R * C;
    unsigned short* dst = outp + (size_t)e * R * C;
    const int c0 = blockIdx.x * 32;
    const int r0 = blockIdx.y * 32;
    const int tx = threadIdx.x & 31, ty = threadIdx.x >> 5;
#pragma unroll
    for (int s = 0; s < 4; ++s)
        tile[ty + s * 8][tx] = f2bf(src[(size_t)(r0 + ty + s * 8) * C + c0 + tx]);
    __syncthreads();
#pragma unroll
    for (int s = 0; s < 4; ++s)
        dst[(size_t)(c0 + ty + s * 8) * R + r0 + tx] = tile[tx][ty + s * 8];
}

// ---------------- GEMM1: hmid = silu(Xg @ Wup), bf16 MFMA -------------------
// 1-D grid of 2048, chunked-XCD swizzle: XCD c owns logical [c*256,(c+1)*256)
// = expert c's entire tile grid -> A/B panels reuse c's private L2.
__global__ __launch_bounds__(256) void moe_gemm1(
    const unsigned short* __restrict__ Xg, const unsigned short* __restrict__ WupT,
    const int* __restrict__ counts, unsigned short* __restrict__ hmid)
{
    __shared__ unsigned short As[BM][BK];
    __shared__ unsigned short Bs[BN][BK];
    const int s_id = blockIdx.x;
    const int l = (s_id & 7) * 256 + (s_id >> 3);  // bijective: 2048 = 8*256
    const int e = l >> 8;                          // expert  (chunk)
    const int bx = l & 15;                         // row-block (fastest)
    const int by = (l >> 4) & 15;                  // n-block
    const int cnt = min(counts[e], CAP);
    const int row0 = bx * BM;
    if (row0 >= cnt) return;
    const int n0 = by * BN;
    const int tid = threadIdx.x;
    const int lane = tid & 63;
    const int wid = tid >> 6;
    const int wm = wid >> 1, wn = wid & 1;

    const unsigned short* Ae = Xg + (size_t)e * CAP * H_DIM;
    const unsigned short* Be = WupT + (size_t)e * (size_t)I_DIM * H_DIM;

    const int sub = lane >> 3;            // 0..7 rows within 1KB chunk
    const int kus = (lane & 7) * 8;       // ushort offset within 64-col row

    f32x4 acc[4][4];
#pragma unroll
    for (int m = 0; m < 4; ++m)
#pragma unroll
        for (int n = 0; n < 4; ++n) acc[m][n] = (f32x4){0.f, 0.f, 0.f, 0.f};

    for (int kt = 0; kt < H_DIM; kt += BK) {
#pragma unroll
        for (int c = 0; c < 4; ++c) {
            const int row = (c * 4 + wid) * 8 + sub;
            gl_lds16(Ae + (size_t)(row0 + row) * H_DIM + kt + kus,
                     (char*)&As[0][0] + (c * 4 + wid) * 1024);
            gl_lds16(Be + (size_t)(n0 + row) * H_DIM + kt + kus,
                     (char*)&Bs[0][0] + (c * 4 + wid) * 1024);
        }
        __syncthreads();
#pragma unroll
        for (int kk = 0; kk < BK; kk += 32) {
            const int koff = kk + 8 * (lane >> 4);
            bf16x8 a[4], b[4];
#pragma unroll
            for (int m = 0; m < 4; ++m)
                a[m] = *(const bf16x8*)&As[wm * 64 + m * 16 + (lane & 15)][koff];
#pragma unroll
            for (int n = 0; n < 4; ++n)
                b[n] = *(const bf16x8*)&Bs[wn * 64 + n * 16 + (lane & 15)][koff];
#pragma unroll
            for (int m = 0; m < 4; ++m)
#pragma unroll
                for (int n = 0; n < 4; ++n)
                    acc[m][n] = __builtin_amdgcn_mfma_f32_16x16x32_bf16(
                        a[m], b[n], acc[m][n], 0, 0, 0);
        }
        __syncthreads();
    }

    unsigned short* He = hmid + (size_t)e * CAP * I_DIM;
#pragma unroll
    for (int m = 0; m < 4; ++m) {
        const int rb = row0 + wm * 64 + m * 16 + ((lane >> 4) << 2);
#pragma unroll
        for (int n = 0; n < 4; ++n) {
            const int col = n0 + wn * 64 + n * 16 + (lane & 15);
#pragma unroll
            for (int j = 0; j < 4; ++j) {
                const float v = acc[m][n][j];
                const float s = v / (1.f + __expf(-v));
                He[(size_t)(rb + j) * I_DIM + col] = f2bf(s);
            }
        }
    }
}

// ---------------- GEMM2: out += w * (hmid @ Wdown), atomic scatter ----------
// 1-D grid of 1024, chunked-XCD swizzle: XCD c = expert c (chunk of 128).
__global__ __launch_bounds__(256) void moe_gemm2(
    const unsigned short* __restrict__ hmid, const unsigned short* __restrict__ WdownT,
    const int* __restrict__ counts, const int* __restrict__ list_tok,
    const float* __restrict__ list_w, float* __restrict__ out)
{
    __shared__ unsigned short As[BM][BK];
    __shared__ unsigned short Bs[BN][BK];
    const int s_id = blockIdx.x;
    const int l = (s_id & 7) * 128 + (s_id >> 3);  // bijective: 1024 = 8*128
    const int e = l >> 7;                          // expert (chunk)
    const int bx = l & 15;                         // row-block (fastest)
    const int by = (l >> 4) & 7;                   // n-block
    const int cnt = min(counts[e], CAP);
    const int row0 = bx * BM;
    if (row0 >= cnt) return;
    const int n0 = by * BN;
    const int tid = threadIdx.x;
    const int lane = tid & 63;
    const int wid = tid >> 6;
    const int wm = wid >> 1, wn = wid & 1;

    const unsigned short* Ae = hmid + (size_t)e * CAP * I_DIM;
    const unsigned short* Be = WdownT + (size_t)e * (size_t)H_DIM * I_DIM;

    const int sub = lane >> 3;
    const int kus = (lane & 7) * 8;

    f32x4 acc[4][4];
#pragma unroll
    for (int m = 0; m < 4; ++m)
#pragma unroll
        for (int n = 0; n < 4; ++n) acc[m][n] = (f32x4){0.f, 0.f, 0.f, 0.f};

    for (int kt = 0; kt < I_DIM; kt += BK) {
#pragma unroll
        for (int c = 0; c < 4; ++c) {
            const int row = (c * 4 + wid) * 8 + sub;
            gl_lds16(Ae + (size_t)(row0 + row) * I_DIM + kt + kus,
                     (char*)&As[0][0] + (c * 4 + wid) * 1024);
            gl_lds16(Be + (size_t)(n0 + row) * I_DIM + kt + kus,
                     (char*)&Bs[0][0] + (c * 4 + wid) * 1024);
        }
        __syncthreads();
#pragma unroll
        for (int kk = 0; kk < BK; kk += 32) {
            const int koff = kk + 8 * (lane >> 4);
            bf16x8 a[4], b[4];
#pragma unroll
            for (int m = 0; m < 4; ++m)
                a[m] = *(const bf16x8*)&As[wm * 64 + m * 16 + (lane & 15)][koff];
#pragma unroll
            for (int n = 0; n < 4; ++n)
                b[n] = *(const bf16x8*)&Bs[wn * 64 + n * 16 + (lane & 15)][koff];
#pragma unroll
            for (int m = 0; m < 4; ++m)
#pragma unroll
                for (int n = 0; n < 4; ++n)
                    acc[m][n] = __builtin_amdgcn_mfma_f32_16x16x32_bf16(
                        a[m], b[n], acc[m][n], 0, 0, 0);
        }
        __syncthreads();
    }

#pragma unroll
    for (int m = 0; m < 4; ++m) {
#pragma unroll
        for (int j = 0; j < 4; ++j) {
            const int gr = row0 + wm * 64 + m * 16 + ((lane >> 4) << 2) + j;
            if (gr < cnt) {
                const int tok = list_tok[e * CAP + gr];
                const float w = list_w[e * CAP + gr];
                float* op = out + (size_t)tok * H_DIM + n0 + wn * 64 + (lane & 15);
#pragma unroll
                for (int n = 0; n < 4; ++n)
                    atomicAdd(op + n * 16, w * acc[m][n][j]);
            }
        }
    }
}

extern "C" void kernel_launch(void* const* d_in, const int* in_sizes, int n_in,
                              void* d_out, int out_size, void* d_ws, size_t ws_size,
                              hipStream_t stream)
{
    const float* x      = (const float*)d_in[0];   // [T, H]
    const float* gate   = (const float*)d_in[1];   // [E, H]
    const float* w_up   = (const float*)d_in[2];   // [E, H, I]
    const float* w_down = (const float*)d_in[3];   // [E, I, H]
    float* out = (float*)d_out;                    // [T, H]

    char* ws = (char*)d_ws;
    int*   counts   = (int*)(ws);                          // 1 KB
    int*   topk_idx = (int*)(ws + 1024);                   // 32 KB
    float* topk_w   = (float*)(ws + 33792);                // 32 KB
    int*   list_tok = (int*)(ws + 66560);                  // 64 KB
    float* list_w   = (float*)(ws + 132096);               // 64 KB
    unsigned short* Xg     = (unsigned short*)(ws + 197632);                  // 32 MB
    unsigned short* WupT   = (unsigned short*)(ws + 197632 + 33554432ull);    // 32 MB
    unsigned short* WdownT = (unsigned short*)(ws + 197632 + 67108864ull);    // 32 MB
    unsigned short* hmid   = (unsigned short*)(ws + 197632 + 100663296ull);   // 64 MB

    hipMemsetAsync(counts, 0, 1024, stream);
    hipMemsetAsync(out, 0, (size_t)out_size * sizeof(float), stream);

    moe_router<<<T_TOK / 4, 256, 0, stream>>>(x, gate, topk_idx, topk_w);
    moe_build<<<T_TOK / 256, 256, 0, stream>>>(topk_idx, topk_w, counts, list_tok, list_w);
    moe_gather<<<dim3(CAP, E_NUM), 256, 0, stream>>>(x, counts, list_tok, Xg);
    transpose_bf16<<<dim3(I_DIM / 32, H_DIM / 32, E_NUM), 256, 0, stream>>>(w_up, WupT, H_DIM, I_DIM);
    transpose_bf16<<<dim3(H_DIM / 32, I_DIM / 32, E_NUM), 256, 0, stream>>>(w_down, WdownT, I_DIM, H_DIM);
    moe_gemm1<<<2048, 256, 0, stream>>>(Xg, WupT, counts, hmid);
    moe_gemm2<<<1024, 256, 0, stream>>>(hmid, WdownT, counts, list_tok, list_w, out);
}

// Round 9
// 412.059 us; speedup vs baseline: 6.8490x; 1.0537x over previous
//
#include <hip/hip_runtime.h>
#include <math.h>

#define T_TOK 4096
#define H_DIM 1024
#define I_DIM 2048
#define E_NUM 8
#define CAP   2048
#define BM 128
#define BN 128
#define BK 64

typedef __attribute__((ext_vector_type(8))) short bf16x8;
typedef __attribute__((ext_vector_type(4))) float f32x4;

__device__ __forceinline__ unsigned short f2bf(float f) {
    union { float f; unsigned int u; } v; v.f = f;
    unsigned int r = v.u + 0x7FFFu + ((v.u >> 16) & 1u);
    return (unsigned short)(r >> 16);
}

__device__ __forceinline__ void gl_lds16(const void* g, void* l) {
    __builtin_amdgcn_global_load_lds(
        (const __attribute__((address_space(1))) void*)g,
        (__attribute__((address_space(3))) void*)l, 16, 0, 0);
}

// ---------------- Router ----------------------------------------------------
__global__ __launch_bounds__(256) void moe_router(
    const float* __restrict__ x, const float* __restrict__ gate,
    int* __restrict__ topk_idx, float* __restrict__ topk_w)
{
    const int wave = threadIdx.x >> 6;
    const int lane = threadIdx.x & 63;
    const int t = blockIdx.x * 4 + wave;

    float acc[E_NUM];
#pragma unroll
    for (int e = 0; e < E_NUM; ++e) acc[e] = 0.f;
    const float* xp = x + (size_t)t * H_DIM;
    for (int k = lane; k < H_DIM; k += 64) {
        const float xv = xp[k];
#pragma unroll
        for (int e = 0; e < E_NUM; ++e) acc[e] += xv * gate[e * H_DIM + k];
    }
#pragma unroll
    for (int e = 0; e < E_NUM; ++e) {
#pragma unroll
        for (int off = 32; off > 0; off >>= 1)
            acc[e] += __shfl_xor(acc[e], off, 64);
    }
    if (lane == 0) {
        float m = acc[0];
#pragma unroll
        for (int e = 1; e < E_NUM; ++e) m = fmaxf(m, acc[e]);
        float p[E_NUM]; float Z = 0.f;
#pragma unroll
        for (int e = 0; e < E_NUM; ++e) { p[e] = expf(acc[e] - m); Z += p[e]; }
        const float invZ = 1.f / Z;
        int i1 = 0, i2 = 0; float v1 = -1.f, v2 = -1.f;
#pragma unroll
        for (int e = 0; e < E_NUM; ++e) {
            const float pe = p[e] * invZ;
            if (pe > v1)      { v2 = v1; i2 = i1; v1 = pe; i1 = e; }
            else if (pe > v2) { v2 = pe; i2 = e; }
        }
        const float s = 1.f / (v1 + v2 + 1e-9f);
        topk_idx[t * 2 + 0] = i1; topk_idx[t * 2 + 1] = i2;
        topk_w[t * 2 + 0] = v1 * s; topk_w[t * 2 + 1] = v2 * s;
    }
}

// ---------------- Build per-expert token lists ------------------------------
__global__ void moe_build(
    const int* __restrict__ topk_idx, const float* __restrict__ topk_w,
    int* __restrict__ counts, int* __restrict__ list_tok, float* __restrict__ list_w)
{
    const int t = blockIdx.x * blockDim.x + threadIdx.x;
    if (t >= T_TOK) return;
#pragma unroll
    for (int k = 0; k < 2; ++k) {
        const int e = topk_idx[t * 2 + k];
        const float w = topk_w[t * 2 + k];
        const int pos = atomicAdd(&counts[e], 1);
        if (pos < CAP) {
            list_tok[e * CAP + pos] = t;
            list_w[e * CAP + pos] = w;
        }
    }
}

// ---------------- Gather X rows -> bf16 Xg[e][CAP][H] -----------------------
__global__ __launch_bounds__(256) void moe_gather(
    const float* __restrict__ x, const int* __restrict__ counts,
    const int* __restrict__ list_tok, unsigned short* __restrict__ Xg)
{
    const int e = blockIdx.y;
    const int r = blockIdx.x;
    if (r >= min(counts[e], CAP)) return;
    const int tok = list_tok[e * CAP + r];
    const float4 v = ((const float4*)(x + (size_t)tok * H_DIM))[threadIdx.x];
    ushort4 o = make_ushort4(f2bf(v.x), f2bf(v.y), f2bf(v.z), f2bf(v.w));
    *(ushort4*)(Xg + (size_t)(e * CAP + r) * H_DIM + threadIdx.x * 4) = o;
}

// ---------------- Transpose-convert: [E][R][C] f32 -> [E][C][R] bf16 --------
// 64x64 tile, float4 vector reads, b128 vector writes via LDS transpose.
__global__ __launch_bounds__(256) void transpose_bf16(
    const float* __restrict__ in, unsigned short* __restrict__ outp, int R, int C)
{
    __shared__ unsigned short t[64][72];   // 72-u16 stride: 16B-aligned rows
    const int e = blockIdx.z;
    const float* src = in + (size_t)e * R * C;
    unsigned short* dst = outp + (size_t)e * R * C;
    const int c0 = blockIdx.x * 64;
    const int r0 = blockIdx.y * 64;
    const int tx = (threadIdx.x & 15) << 2;   // col 0..60 step 4
    const int ty = threadIdx.x >> 4;          // row 0..15
#pragma unroll
    for (int s = 0; s < 4; ++s) {
        const int r = ty + s * 16;
        const float4 v = *(const float4*)&src[(size_t)(r0 + r) * C + c0 + tx];
        t[tx + 0][r] = f2bf(v.x);
        t[tx + 1][r] = f2bf(v.y);
        t[tx + 2][r] = f2bf(v.z);
        t[tx + 3][r] = f2bf(v.w);
    }
    __syncthreads();
    const int cc = threadIdx.x >> 3;          // 0..31
    const int rr = (threadIdx.x & 7) << 3;    // 0..56 step 8
#pragma unroll
    for (int s = 0; s < 2; ++s) {
        const int c = cc + s * 32;
        *(bf16x8*)&dst[(size_t)(c0 + c) * R + r0 + rr] = *(const bf16x8*)&t[c][rr];
    }
}

// ---------------- GEMM1: hmid = silu(Xg @ Wup), dbuf 2-phase ----------------
// 1-D grid 2048, chunked-XCD swizzle: XCD c == expert c.
__global__ __launch_bounds__(256) void moe_gemm1(
    const unsigned short* __restrict__ Xg, const unsigned short* __restrict__ WupT,
    const int* __restrict__ counts, unsigned short* __restrict__ hmid)
{
    __shared__ unsigned short As[2][BM][BK];
    __shared__ unsigned short Bs[2][BN][BK];
    const int s_id = blockIdx.x;
    const int l = (s_id & 7) * 256 + (s_id >> 3);  // bijective: 2048 = 8*256
    const int e = l >> 8;
    const int bx = l & 15;
    const int by = (l >> 4) & 15;
    const int cnt = min(counts[e], CAP);
    const int row0 = bx * BM;
    if (row0 >= cnt) return;
    const int n0 = by * BN;
    const int tid = threadIdx.x;
    const int lane = tid & 63;
    const int wid = tid >> 6;
    const int wm = wid >> 1, wn = wid & 1;

    const unsigned short* Ae = Xg + (size_t)e * CAP * H_DIM;
    const unsigned short* Be = WupT + (size_t)e * (size_t)I_DIM * H_DIM;

    const int sub = lane >> 3;
    const int kus = (lane & 7) * 8;

#define STAGE1(buf, kt)                                                       \
    {                                                                         \
        _Pragma("unroll")                                                     \
        for (int c = 0; c < 4; ++c) {                                         \
            const int row = (c * 4 + wid) * 8 + sub;                          \
            gl_lds16(Ae + (size_t)(row0 + row) * H_DIM + (kt) + kus,          \
                     (char*)&As[buf][0][0] + (c * 4 + wid) * 1024);           \
            gl_lds16(Be + (size_t)(n0 + row) * H_DIM + (kt) + kus,            \
                     (char*)&Bs[buf][0][0] + (c * 4 + wid) * 1024);           \
        }                                                                     \
    }

    f32x4 acc[4][4];
#pragma unroll
    for (int m = 0; m < 4; ++m)
#pragma unroll
        for (int n = 0; n < 4; ++n) acc[m][n] = (f32x4){0.f, 0.f, 0.f, 0.f};

    STAGE1(0, 0);
    __syncthreads();
    int cur = 0;
    for (int kt = 0; kt < H_DIM; kt += BK) {
        if (kt + BK < H_DIM) STAGE1(cur ^ 1, kt + BK);
#pragma unroll
        for (int kk = 0; kk < BK; kk += 32) {
            const int koff = kk + 8 * (lane >> 4);
            bf16x8 a[4], b[4];
#pragma unroll
            for (int m = 0; m < 4; ++m)
                a[m] = *(const bf16x8*)&As[cur][wm * 64 + m * 16 + (lane & 15)][koff];
#pragma unroll
            for (int n = 0; n < 4; ++n)
                b[n] = *(const bf16x8*)&Bs[cur][wn * 64 + n * 16 + (lane & 15)][koff];
#pragma unroll
            for (int m = 0; m < 4; ++m)
#pragma unroll
                for (int n = 0; n < 4; ++n)
                    acc[m][n] = __builtin_amdgcn_mfma_f32_16x16x32_bf16(
                        a[m], b[n], acc[m][n], 0, 0, 0);
        }
        __syncthreads();           // drains vmcnt(0): next tile landed
        cur ^= 1;
    }
#undef STAGE1

    unsigned short* He = hmid + (size_t)e * CAP * I_DIM;
#pragma unroll
    for (int m = 0; m < 4; ++m) {
        const int rb = row0 + wm * 64 + m * 16 + ((lane >> 4) << 2);
#pragma unroll
        for (int n = 0; n < 4; ++n) {
            const int col = n0 + wn * 64 + n * 16 + (lane & 15);
#pragma unroll
            for (int j = 0; j < 4; ++j) {
                const float v = acc[m][n][j];
                const float s = v / (1.f + __expf(-v));
                He[(size_t)(rb + j) * I_DIM + col] = f2bf(s);
            }
        }
    }
}

// ---------------- GEMM2: out += w * (hmid @ Wdown), K-split x2, dbuf --------
// 1-D grid 2048, chunked-XCD swizzle: XCD c == expert c (chunk 256).
__global__ __launch_bounds__(256) void moe_gemm2(
    const unsigned short* __restrict__ hmid, const unsigned short* __restrict__ WdownT,
    const int* __restrict__ counts, const int* __restrict__ list_tok,
    const float* __restrict__ list_w, float* __restrict__ out)
{
    __shared__ unsigned short As[2][BM][BK];
    __shared__ unsigned short Bs[2][BN][BK];
    const int s_id = blockIdx.x;
    const int l = (s_id & 7) * 256 + (s_id >> 3);  // bijective: 2048 = 8*256
    const int e = l >> 8;
    const int bx = l & 15;
    const int by = (l >> 4) & 7;
    const int kh = (l >> 7) & 1;                   // K-half: [0,1024) or [1024,2048)
    const int cnt = min(counts[e], CAP);
    const int row0 = bx * BM;
    if (row0 >= cnt) return;
    const int n0 = by * BN;
    const int kbase = kh * (I_DIM / 2);
    const int tid = threadIdx.x;
    const int lane = tid & 63;
    const int wid = tid >> 6;
    const int wm = wid >> 1, wn = wid & 1;

    const unsigned short* Ae = hmid + (size_t)e * CAP * I_DIM;
    const unsigned short* Be = WdownT + (size_t)e * (size_t)H_DIM * I_DIM;

    const int sub = lane >> 3;
    const int kus = (lane & 7) * 8;

#define STAGE2(buf, kt)                                                       \
    {                                                                         \
        _Pragma("unroll")                                                     \
        for (int c = 0; c < 4; ++c) {                                         \
            const int row = (c * 4 + wid) * 8 + sub;                          \
            gl_lds16(Ae + (size_t)(row0 + row) * I_DIM + kbase + (kt) + kus,  \
                     (char*)&As[buf][0][0] + (c * 4 + wid) * 1024);           \
            gl_lds16(Be + (size_t)(n0 + row) * I_DIM + kbase + (kt) + kus,    \
                     (char*)&Bs[buf][0][0] + (c * 4 + wid) * 1024);           \
        }                                                                     \
    }

    f32x4 acc[4][4];
#pragma unroll
    for (int m = 0; m < 4; ++m)
#pragma unroll
        for (int n = 0; n < 4; ++n) acc[m][n] = (f32x4){0.f, 0.f, 0.f, 0.f};

    STAGE2(0, 0);
    __syncthreads();
    int cur = 0;
    for (int kt = 0; kt < I_DIM / 2; kt += BK) {
        if (kt + BK < I_DIM / 2) STAGE2(cur ^ 1, kt + BK);
#pragma unroll
        for (int kk = 0; kk < BK; kk += 32) {
            const int koff = kk + 8 * (lane >> 4);
            bf16x8 a[4], b[4];
#pragma unroll
            for (int m = 0; m < 4; ++m)
                a[m] = *(const bf16x8*)&As[cur][wm * 64 + m * 16 + (lane & 15)][koff];
#pragma unroll
            for (int n = 0; n < 4; ++n)
                b[n] = *(const bf16x8*)&Bs[cur][wn * 64 + n * 16 + (lane & 15)][koff];
#pragma unroll
            for (int m = 0; m < 4; ++m)
#pragma unroll
                for (int n = 0; n < 4; ++n)
                    acc[m][n] = __builtin_amdgcn_mfma_f32_16x16x32_bf16(
                        a[m], b[n], acc[m][n], 0, 0, 0);
        }
        __syncthreads();
        cur ^= 1;
    }
#undef STAGE2

#pragma unroll
    for (int m = 0; m < 4; ++m) {
#pragma unroll
        for (int j = 0; j < 4; ++j) {
            const int gr = row0 + wm * 64 + m * 16 + ((lane >> 4) << 2) + j;
            if (gr < cnt) {
                const int tok = list_tok[e * CAP + gr];
                const float w = list_w[e * CAP + gr];
                float* op = out + (size_t)tok * H_DIM + n0 + wn * 64 + (lane & 15);
#pragma unroll
                for (int n = 0; n < 4; ++n)
                    atomicAdd(op + n * 16, w * acc[m][n][j]);
            }
        }
    }
}

extern "C" void kernel_launch(void* const* d_in, const int* in_sizes, int n_in,
                              void* d_out, int out_size, void* d_ws, size_t ws_size,
                              hipStream_t stream)
{
    const float* x      = (const float*)d_in[0];   // [T, H]
    const float* gate   = (const float*)d_in[1];   // [E, H]
    const float* w_up   = (const float*)d_in[2];   // [E, H, I]
    const float* w_down = (const float*)d_in[3];   // [E, I, H]
    float* out = (float*)d_out;                    // [T, H]

    char* ws = (char*)d_ws;
    int*   counts   = (int*)(ws);                          // 1 KB
    int*   topk_idx = (int*)(ws + 1024);                   // 32 KB
    float* topk_w   = (float*)(ws + 33792);                // 32 KB
    int*   list_tok = (int*)(ws + 66560);                  // 64 KB
    float* list_w   = (float*)(ws + 132096);               // 64 KB
    unsigned short* Xg     = (unsigned short*)(ws + 197632);                  // 32 MB
    unsigned short* WupT   = (unsigned short*)(ws + 197632 + 33554432ull);    // 32 MB
    unsigned short* WdownT = (unsigned short*)(ws + 197632 + 67108864ull);    // 32 MB
    unsigned short* hmid   = (unsigned short*)(ws + 197632 + 100663296ull);   // 64 MB

    hipMemsetAsync(counts, 0, 1024, stream);
    hipMemsetAsync(out, 0, (size_t)out_size * sizeof(float), stream);

    moe_router<<<T_TOK / 4, 256, 0, stream>>>(x, gate, topk_idx, topk_w);
    moe_build<<<T_TOK / 256, 256, 0, stream>>>(topk_idx, topk_w, counts, list_tok, list_w);
    moe_gather<<<dim3(CAP, E_NUM), 256, 0, stream>>>(x, counts, list_tok, Xg);
    transpose_bf16<<<dim3(I_DIM / 64, H_DIM / 64, E_NUM), 256, 0, stream>>>(w_up, WupT, H_DIM, I_DIM);
    transpose_bf16<<<dim3(H_DIM / 64, I_DIM / 64, E_NUM), 256, 0, stream>>>(w_down, WdownT, I_DIM, H_DIM);
    moe_gemm1<<<2048, 256, 0, stream>>>(Xg, WupT, counts, hmid);
    moe_gemm2<<<2048, 256, 0, stream>>>(hmid, WdownT, counts, list_tok, list_w, out);
}